// Round 2
// baseline (516.151 us; speedup 1.0000x reference)
//
#include <hip/hip_runtime.h>
#include <math.h>

// RNNT joint + log_softmax over vocab.
//   f: [B,T,V] fp32, g: [B,U,V] fp32
//   out[b,t,u,v] = x - (max_v x + log(sum_v exp(x - max_v x))),  x = f[b,t,v] + g[b,u,v]
// B=4, T=256, U=128, V=1024.
// One wave (64 lanes) per (b,t,u) row: 1024 floats = 64 lanes x 4 float4,
// entire row lives in registers; wave shuffle butterfly reductions only.

#define RB 4
#define RT 256
#define RU 128
#define RV 1024

typedef float nfloat4 __attribute__((ext_vector_type(4)));  // native vec for nontemporal store

__global__ __launch_bounds__(256, 4) void rnnt_joint_ls_kernel(
    const float* __restrict__ f,
    const float* __restrict__ g,
    float* __restrict__ out)
{
    const int wave = threadIdx.x >> 6;
    const int lane = threadIdx.x & 63;
    const long long row = (long long)blockIdx.x * 4 + wave;   // row in [0, B*T*U)

    // row = (b*T + t)*U + u
    const int u  = (int)(row % RU);
    const int bt = (int)(row / RU);          // b*T + t
    const int b  = bt / RT;

    const float4* __restrict__ f4 = (const float4*)(f + (size_t)bt * RV);
    const float4* __restrict__ g4 = (const float4*)(g + ((size_t)b * RU + u) * RV);
    nfloat4* __restrict__ o4 = (nfloat4*)(out + (size_t)row * RV);

    float4 x[4];
#pragma unroll
    for (int i = 0; i < 4; ++i) {
        float4 fv = f4[lane + 64 * i];
        float4 gv = g4[lane + 64 * i];
        x[i].x = fv.x + gv.x;
        x[i].y = fv.y + gv.y;
        x[i].z = fv.z + gv.z;
        x[i].w = fv.w + gv.w;
    }

    // ---- wave max reduction ----
    float m = -INFINITY;
#pragma unroll
    for (int i = 0; i < 4; ++i) {
        m = fmaxf(m, fmaxf(fmaxf(x[i].x, x[i].y), fmaxf(x[i].z, x[i].w)));
    }
#pragma unroll
    for (int off = 32; off > 0; off >>= 1) {
        m = fmaxf(m, __shfl_xor(m, off, 64));
    }

    // ---- wave sum(exp(x - m)) reduction ----
    float s = 0.0f;
#pragma unroll
    for (int i = 0; i < 4; ++i) {
        s += __expf(x[i].x - m);
        s += __expf(x[i].y - m);
        s += __expf(x[i].z - m);
        s += __expf(x[i].w - m);
    }
#pragma unroll
    for (int off = 32; off > 0; off >>= 1) {
        s += __shfl_xor(s, off, 64);
    }

    const float M = m + __logf(s);

    // ---- streaming write (non-temporal: output is never re-read) ----
#pragma unroll
    for (int i = 0; i < 4; ++i) {
        nfloat4 y;
        y.x = x[i].x - M;
        y.y = x[i].y - M;
        y.z = x[i].z - M;
        y.w = x[i].w - M;
        __builtin_nontemporal_store(y, &o4[lane + 64 * i]);
    }
}

extern "C" void kernel_launch(void* const* d_in, const int* in_sizes, int n_in,
                              void* d_out, int out_size, void* d_ws, size_t ws_size,
                              hipStream_t stream) {
    const float* f = (const float*)d_in[0];   // [B,T,V]
    const float* g = (const float*)d_in[1];   // [B,U,V]
    float* out = (float*)d_out;               // [B,T,U,V]

    const int rows = RB * RT * RU;            // 131072
    dim3 grid(rows / 4);                      // 4 waves per block
    dim3 block(256);
    rnnt_joint_ls_kernel<<<grid, block, 0, stream>>>(f, g, out);
}